// Round 20
// baseline (115.831 us; speedup 1.0000x reference)
//
#include <hip/hip_runtime.h>
#include <hip/hip_bf16.h>
#include <math.h>

#define BB 2
#define TT 2048
#define CCH 1024
#define HH 16
#define DD 64
#define BT (BB*TT)     // 4096
#define N3 (3*CCH)     // 3072

typedef __attribute__((ext_vector_type(8))) short short8;
typedef __attribute__((ext_vector_type(4))) float f32x4;
typedef __attribute__((ext_vector_type(16))) float f32x16;

__device__ __forceinline__ unsigned short f2bf(float f) {
  unsigned int u = __float_as_uint(f);
  unsigned int r = (u + 0x7FFFu + ((u >> 16) & 1u)) >> 16;  // RNE
  return (unsigned short)r;
}
__device__ __forceinline__ int cvtpk(float lo, float hi) {
  int r;
  asm("v_cvt_pk_bf16_f32 %0, %1, %2" : "=v"(r) : "v"(lo), "v"(hi));
  return r;
}
__device__ __forceinline__ void plswap(int &a, int &b) {
  asm("v_permlane32_swap_b32 %0, %1" : "+v"(a), "+v"(b));
}
__device__ __forceinline__ float fexp2(float x) {   // native v_exp_f32: 2^x, 1 inst
  float r;
  asm("v_exp_f32 %0, %1" : "=v"(r) : "v"(x));
  return r;
}
__device__ __forceinline__ void gload_lds16(const unsigned short* g, unsigned short* l) {
  __builtin_amdgcn_global_load_lds((const __attribute__((address_space(1))) void*)g,
                                   (__attribute__((address_space(3))) void*)l, 16, 0, 0);
}
__device__ __forceinline__ float fmax3(float a, float b, float c) {
  return fmaxf(fmaxf(a, b), c);   // fuses to v_max3_f32
}

// Fragment-ordered layouts (per-bh buffers of TT*DD bf16):
//  row-frag (Q and K):  addr(r, d) = ((r>>5)*4 + (d>>4))*512 + ((d>>3)&1)*256 + (r&31)*8 + (d&7)
//  col-frag (V):        addr(t, d) = (((t>>6)*2 + (d>>5))*4 + ((t>>4)&3))*512
//                                    + (((t>>3)&1)*32 + (d&31))*8 + (t&7)

// ---------------- fused prep: x->bf16 convert + both weight transposes (one launch) ----------------
__global__ __launch_bounds__(256) void k_prep(const float* __restrict__ x,
                                              const float* __restrict__ W_qkv,
                                              const float* __restrict__ W_proj,
                                              unsigned short* __restrict__ Xb,
                                              unsigned short* __restrict__ Wt_qkv,
                                              unsigned short* __restrict__ Wt_proj) {
  __shared__ float tile[32][33];
  int id = blockIdx.x;
  int tid = threadIdx.x;
  if (id < 2048) {
    int i = id * 256 + tid;
    const float4 a = *(const float4*)(x + (size_t)i * 8);
    const float4 b = *(const float4*)(x + (size_t)i * 8 + 4);
    short8 v;
    v[0] = f2bf(a.x); v[1] = f2bf(a.y); v[2] = f2bf(a.z); v[3] = f2bf(a.w);
    v[4] = f2bf(b.x); v[5] = f2bf(b.y); v[6] = f2bf(b.z); v[7] = f2bf(b.w);
    *(short8*)(Xb + (size_t)i * 8) = v;
    return;
  }
  const float* in;
  unsigned short* out;
  int R, Cn, tc, tr;
  if (id < 2048 + 3072) {             // W_qkv transpose
    int u = id - 2048;
    in = W_qkv; out = Wt_qkv; R = CCH; Cn = N3;
    tc = (u % 96) * 32; tr = (u / 96) * 32;
  } else {                            // W_proj transpose
    int u = id - 5120;
    in = W_proj; out = Wt_proj; R = CCH; Cn = CCH;
    tc = (u % 32) * 32; tr = (u / 32) * 32;
  }
  int lx = tid & 31;
  int ly = tid >> 5;
#pragma unroll
  for (int i = 0; i < 32; i += 8)
    tile[ly + i][lx] = in[(size_t)(tr + ly + i) * Cn + tc + lx];
  __syncthreads();
#pragma unroll
  for (int i = 0; i < 32; i += 8)
    out[(size_t)(tc + ly + i) * R + tr + lx] = f2bf(tile[lx][ly + i]);
}

// ---------------- QKV GEMM (m97 pattern) -> fragment-ordered Qf(scaled), Kf, Vf ----------------
__global__ __launch_bounds__(256) void k_qkv_gemm(const unsigned short* __restrict__ Xb,
                                                  const unsigned short* __restrict__ Wt,
                                                  const float* __restrict__ bias,
                                                  unsigned short* __restrict__ Qf,
                                                  unsigned short* __restrict__ Kf,
                                                  unsigned short* __restrict__ Vf) {
  __shared__ __align__(16) unsigned short As[128 * 32];
  __shared__ __align__(16) unsigned short Bs[128 * 32];
  int tid = threadIdx.x;
  int mb = blockIdx.x * 128;
  int nb = blockIdx.y * 128;
  int wid = tid >> 6, lane = tid & 63;
  int wr = (wid >> 1) * 64, wc = (wid & 1) * 64;
  int l15 = lane & 15, l4 = lane >> 4;
  int l16 = lane >> 2, lc = (lane & 3) * 8;
  f32x4 acc[4][4];
#pragma unroll
  for (int a = 0; a < 4; ++a)
#pragma unroll
    for (int b = 0; b < 4; ++b)
#pragma unroll
      for (int j = 0; j < 4; ++j) acc[a][b][j] = 0.0f;

  for (int kb = 0; kb < CCH; kb += 32) {
#pragma unroll
    for (int i = 0; i < 2; ++i) {
      int arow = wid * 32 + i * 16;
      gload_lds16(Xb + (size_t)(mb + arow + l16) * CCH + kb + lc, &As[arow * 32]);
      gload_lds16(Wt + (size_t)(nb + arow + l16) * CCH + kb + lc, &Bs[arow * 32]);
    }
    __syncthreads();
    short8 af[4], bfr[4];
#pragma unroll
    for (int mt = 0; mt < 4; ++mt) af[mt] = *(const short8*)(&As[(wr + mt * 16 + l15) * 32 + l4 * 8]);
#pragma unroll
    for (int nt = 0; nt < 4; ++nt) bfr[nt] = *(const short8*)(&Bs[(wc + nt * 16 + l15) * 32 + l4 * 8]);
#pragma unroll
    for (int mt = 0; mt < 4; ++mt)
#pragma unroll
      for (int nt = 0; nt < 4; ++nt)
        acc[mt][nt] = __builtin_amdgcn_mfma_f32_16x16x32_bf16(af[mt], bfr[nt], acc[mt][nt], 0, 0, 0);
    __syncthreads();
  }

#pragma unroll
  for (int mt = 0; mt < 4; ++mt) {
#pragma unroll
    for (int nt = 0; nt < 4; ++nt) {
      int gcol = nb + wc + nt * 16 + l15;
      int which = gcol >> 10;
      int cc = gcol & 1023;
      int hh = cc >> 6, d = cc & 63;
      float bv = bias[gcol];
#pragma unroll
      for (int j = 0; j < 4; ++j) {
        int grow = mb + wr + mt * 16 + l4 * 4 + j;
        int b = grow >> 11, t = grow & 2047;
        float v = acc[mt][nt][j] + bv;
        size_t bh = (size_t)(b * HH + hh) * TT * DD;
        if (which == 2) {
          size_t a = (size_t)((((t >> 6) * 2 + (d >> 5)) * 4 + ((t >> 4) & 3)) * 512
                             + (((t >> 3) & 1) * 32 + (d & 31)) * 8 + (t & 7));
          Vf[bh + a] = f2bf(v);
        } else {
          size_t a = (size_t)(((t >> 5) * 4 + (d >> 4)) * 512
                             + ((d >> 3) & 1) * 256 + (t & 31) * 8 + (d & 7));
          if (which == 0) Qf[bh + a] = f2bf(v * 0.18033688f);  // sm_scale * log2(e)
          else            Kf[bh + a] = f2bf(v);
        }
      }
    }
  }
}

// ---------------- causal flash attention: LDS-free + 2-deep register pipeline (T14) ----------------
// Block = 32 q-rows x 2 independent waves (even/odd tiles). Tile t+2's K/V fragment
// loads issue BEFORE computing tile t (named A/B buffers, loop unrolled by 2 so all
// indexing is compile-time). Compiler's per-use waitcnt waits only tile-t loads.
#define AT_ISSUE(KF, VF, tt)                                                                     \
  {                                                                                              \
    int _t = (tt);                                                                               \
    _Pragma("unroll")                                                                            \
    for (int t32 = 0; t32 < 2; ++t32)                                                            \
      _Pragma("unroll")                                                                          \
      for (int m = 0; m < 4; ++m)                                                                \
        KF[t32][m] = *(const short8*)(Kp + (size_t)((_t * 2 + t32) * 4 + m) * 512 + lane * 8);   \
    _Pragma("unroll")                                                                            \
    for (int dt = 0; dt < 2; ++dt)                                                               \
      _Pragma("unroll")                                                                          \
      for (int g = 0; g < 4; ++g)                                                                \
        VF[dt][g] = *(const short8*)(Vp + (size_t)((_t * 2 + dt) * 4 + g) * 512 + lane * 8);     \
  }

#define AT_COMPUTE(KF, VF, tt)                                                                   \
  {                                                                                              \
    int kvb = (tt) * 64;                                                                         \
    f32x16 st[2];                                                                                \
    __builtin_amdgcn_s_setprio(1);                                                               \
    _Pragma("unroll")                                                                            \
    for (int t32 = 0; t32 < 2; ++t32) {                                                          \
      st[t32] = __builtin_amdgcn_mfma_f32_32x32x16_bf16(KF[t32][0], qf[0], zv, 0, 0, 0);         \
      _Pragma("unroll")                                                                          \
      for (int m = 1; m < 4; ++m)                                                                \
        st[t32] = __builtin_amdgcn_mfma_f32_32x32x16_bf16(KF[t32][m], qf[m], st[t32], 0, 0, 0);  \
    }                                                                                            \
    __builtin_amdgcn_s_setprio(0);                                                               \
    if (kvb + 63 > q0) {                                                                         \
      _Pragma("unroll")                                                                          \
      for (int t32 = 0; t32 < 2; ++t32)                                                          \
        _Pragma("unroll")                                                                        \
        for (int r = 0; r < 16; ++r) {                                                           \
          int kvg = kvb + t32 * 32 + (r & 3) + 8 * (r >> 2) + 4 * h;                             \
          if (kvg > qrow) st[t32][r] = -1e30f;                                                   \
        }                                                                                        \
    }                                                                                            \
    float A = st[0][0], B = st[0][1], C = st[0][2], Dv = st[0][3];                               \
    _Pragma("unroll")                                                                            \
    for (int r = 4; r < 16; r += 4) {                                                            \
      A = fmax3(A, st[0][r], st[0][r + 1]);                                                      \
      B = fmax3(B, st[0][r + 2], st[0][r + 3]);                                                  \
      C = fmax3(C, st[1][r - 4], st[1][r - 3]);                                                  \
      Dv = fmax3(Dv, st[1][r - 2], st[1][r - 1]);                                                \
    }                                                                                            \
    C = fmax3(C, st[1][12], st[1][13]);                                                          \
    Dv = fmax3(Dv, st[1][14], st[1][15]);                                                        \
    float mx = fmaxf(fmax3(A, B, C), Dv);                                                        \
    mx = fmaxf(mx, __shfl_xor(mx, 32));                                                          \
    if (__any(mx - mrun > 8.0f)) {                                                               \
      float mnew = fmaxf(mrun, mx);                                                              \
      float alpha = fexp2(mrun - mnew);                                                          \
      lrun *= alpha;                                                                             \
      _Pragma("unroll")                                                                          \
      for (int dt = 0; dt < 2; ++dt)                                                             \
        _Pragma("unroll")                                                                        \
        for (int r = 0; r < 16; ++r) po[dt][r] *= alpha;                                         \
      mrun = mnew;                                                                               \
    }                                                                                            \
    float sum = 0.0f;                                                                            \
    _Pragma("unroll")                                                                            \
    for (int t32 = 0; t32 < 2; ++t32)                                                            \
      _Pragma("unroll")                                                                          \
      for (int r = 0; r < 16; ++r) {                                                             \
        float p = fexp2(st[t32][r] - mrun);                                                      \
        st[t32][r] = p;                                                                          \
        sum += p;                                                                                \
      }                                                                                          \
    sum += __shfl_xor(sum, 32);                                                                  \
    lrun += sum;                                                                                 \
    short8 pf[4];                                                                                \
    _Pragma("unroll")                                                                            \
    for (int g = 0; g < 4; ++g) {                                                                \
      int t32 = g >> 1, r0 = (g & 1) * 8;                                                        \
      int a = cvtpk(st[t32][r0 + 0], st[t32][r0 + 1]);                                           \
      int b = cvtpk(st[t32][r0 + 4], st[t32][r0 + 5]);                                           \
      plswap(a, b);                                                                              \
      int c = cvtpk(st[t32][r0 + 2], st[t32][r0 + 3]);                                           \
      int d = cvtpk(st[t32][r0 + 6], st[t32][r0 + 7]);                                           \
      plswap(c, d);                                                                              \
      union { int w[4]; short8 s; } un;                                                          \
      un.w[0] = a; un.w[1] = c; un.w[2] = b; un.w[3] = d;                                        \
      pf[g] = un.s;                                                                              \
    }                                                                                            \
    __builtin_amdgcn_s_setprio(1);                                                               \
    _Pragma("unroll")                                                                            \
    for (int dt = 0; dt < 2; ++dt)                                                               \
      _Pragma("unroll")                                                                          \
      for (int g = 0; g < 4; ++g)                                                                \
        po[dt] = __builtin_amdgcn_mfma_f32_32x32x16_bf16(VF[dt][g], pf[g], po[dt], 0, 0, 0);     \
    __builtin_amdgcn_s_setprio(0);                                                               \
  }

__global__ __launch_bounds__(128) void k_attn(const unsigned short* __restrict__ Qf,
                                              const unsigned short* __restrict__ Kf,
                                              const unsigned short* __restrict__ Vf,
                                              unsigned short* __restrict__ Y) {
  __shared__ float ex[64 * 33];
  __shared__ float exml[128];
  int tid = threadIdx.x;
  int jx = blockIdx.x;
  int j = 63 - (jx >> 5);
  int bh = jx & 31;
  int wid = tid >> 6, lane = tid & 63;
  int l31 = lane & 31, h = lane >> 5;
  int q0 = j * 32;
  int qrow = q0 + l31;
  int tmax = j >> 1;

  const unsigned short* Qp = Qf + (size_t)bh * TT * DD;
  const unsigned short* Kp = Kf + (size_t)bh * TT * DD;
  const unsigned short* Vp = Vf + (size_t)bh * TT * DD;

  short8 qf[4];
#pragma unroll
  for (int m = 0; m < 4; ++m)
    qf[m] = *(const short8*)(Qp + (size_t)(j * 4 + m) * 512 + lane * 8);

  f32x16 zv;
#pragma unroll
  for (int r = 0; r < 16; ++r) zv[r] = 0.0f;
  f32x16 po[2];
  po[0] = zv; po[1] = zv;
  float mrun = -1e30f, lrun = 0.0f;

  short8 kfA[2][4], vfA[2][4], kfB[2][4], vfB[2][4];
  int t = wid;
  if (t <= tmax) {
    AT_ISSUE(kfA, vfA, t);
    while (true) {
      int tn = t + 2;
      if (tn <= tmax) AT_ISSUE(kfB, vfB, tn);      // next tile's loads in flight
      __builtin_amdgcn_sched_barrier(0);           // pin: issue before compute
      AT_COMPUTE(kfA, vfA, t);
      if (tn > tmax) break;
      t = tn;
      tn = t + 2;
      if (tn <= tmax) AT_ISSUE(kfA, vfA, tn);
      __builtin_amdgcn_sched_barrier(0);
      AT_COMPUTE(kfB, vfB, t);
      if (tn > tmax) break;
      t = tn;
    }
  }

  __syncthreads();
  if (wid == 1) {
#pragma unroll
    for (int dt = 0; dt < 2; ++dt)
#pragma unroll
      for (int r = 0; r < 16; ++r) ex[lane * 33 + dt * 16 + r] = po[dt][r];
    exml[lane] = mrun;
    exml[64 + lane] = lrun;
  }
  __syncthreads();
  if (wid == 0) {
    float m1 = exml[lane], l1 = exml[64 + lane];
    float M = fmaxf(mrun, m1);
    float a0 = fexp2(mrun - M), a1 = fexp2(m1 - M);
    float inv = 1.0f / (lrun * a0 + l1 * a1);
    a0 *= inv; a1 *= inv;
    int b = bh >> 4, hh = bh & 15;
    unsigned short* yp = Y + ((size_t)(b * TT + qrow)) * CCH + hh * DD;
#pragma unroll
    for (int dt = 0; dt < 2; ++dt)
#pragma unroll
      for (int r = 0; r < 16; r += 2) {
        int d = dt * 32 + (r & 3) + 8 * (r >> 2) + 4 * h;
        float v0 = po[dt][r]     * a0 + ex[lane * 33 + dt * 16 + r]     * a1;
        float v1 = po[dt][r + 1] * a0 + ex[lane * 33 + dt * 16 + r + 1] * a1;
        *(int*)(yp + d) = cvtpk(v0, v1);
      }
  }
}

// ---------------- proj GEMM (m97 pattern): Yb bf16 @ Wt_proj bf16 + bias -> f32 out ----------------
__global__ __launch_bounds__(256) void k_proj_gemm(const unsigned short* __restrict__ Yb,
                                                   const unsigned short* __restrict__ Wt,
                                                   const float* __restrict__ bias,
                                                   float* __restrict__ Out) {
  __shared__ __align__(16) unsigned short As[128 * 32];
  __shared__ __align__(16) unsigned short Bs[128 * 32];
  int tid = threadIdx.x;
  int mb = blockIdx.x * 128;
  int nb = blockIdx.y * 128;
  int wid = tid >> 6, lane = tid & 63;
  int wr = (wid >> 1) * 64, wc = (wid & 1) * 64;
  int l15 = lane & 15, l4 = lane >> 4;
  int l16 = lane >> 2, lc = (lane & 3) * 8;
  f32x4 acc[4][4];
#pragma unroll
  for (int a = 0; a < 4; ++a)
#pragma unroll
    for (int b = 0; b < 4; ++b)
#pragma unroll
      for (int j = 0; j < 4; ++j) acc[a][b][j] = 0.0f;

  for (int kb = 0; kb < CCH; kb += 32) {
#pragma unroll
    for (int i = 0; i < 2; ++i) {
      int arow = wid * 32 + i * 16;
      gload_lds16(Yb + (size_t)(mb + arow + l16) * CCH + kb + lc, &As[arow * 32]);
      gload_lds16(Wt + (size_t)(nb + arow + l16) * CCH + kb + lc, &Bs[arow * 32]);
    }
    __syncthreads();
    short8 af[4], bfr[4];
#pragma unroll
    for (int mt = 0; mt < 4; ++mt) af[mt] = *(const short8*)(&As[(wr + mt * 16 + l15) * 32 + l4 * 8]);
#pragma unroll
    for (int nt = 0; nt < 4; ++nt) bfr[nt] = *(const short8*)(&Bs[(wc + nt * 16 + l15) * 32 + l4 * 8]);
#pragma unroll
    for (int mt = 0; mt < 4; ++mt)
#pragma unroll
      for (int nt = 0; nt < 4; ++nt)
        acc[mt][nt] = __builtin_amdgcn_mfma_f32_16x16x32_bf16(af[mt], bfr[nt], acc[mt][nt], 0, 0, 0);
    __syncthreads();
  }

#pragma unroll
  for (int mt = 0; mt < 4; ++mt) {
#pragma unroll
    for (int nt = 0; nt < 4; ++nt) {
      int gcol = nb + wc + nt * 16 + l15;
      float bv = bias[gcol];
#pragma unroll
      for (int j = 0; j < 4; ++j) {
        int grow = mb + wr + mt * 16 + l4 * 4 + j;
        Out[(size_t)grow * CCH + gcol] = acc[mt][nt][j] + bv;
      }
    }
  }
}

extern "C" void kernel_launch(void* const* d_in, const int* in_sizes, int n_in,
                              void* d_out, int out_size, void* d_ws, size_t ws_size,
                              hipStream_t stream) {
  const float* x      = (const float*)d_in[0];
  const float* W_qkv  = (const float*)d_in[1];
  const float* b_qkv  = (const float*)d_in[2];
  const float* W_proj = (const float*)d_in[3];
  const float* b_proj = (const float*)d_in[4];
  float* out = (float*)d_out;

  char* ws = (char*)d_ws;
  size_t off = 0;
  unsigned short* Wt_qkv  = (unsigned short*)(ws + off); off += (size_t)N3 * CCH * 2;
  unsigned short* Wt_proj = (unsigned short*)(ws + off); off += (size_t)CCH * CCH * 2;
  unsigned short* Xb      = (unsigned short*)(ws + off); off += (size_t)BT * CCH * 2;
  unsigned short* Qfb     = (unsigned short*)(ws + off); off += (size_t)BT * CCH * 2;
  unsigned short* Kfb     = (unsigned short*)(ws + off); off += (size_t)BT * CCH * 2;
  unsigned short* Vfb     = (unsigned short*)(ws + off); off += (size_t)BT * CCH * 2;
  unsigned short* Yb      = (unsigned short*)(ws + off); off += (size_t)BT * CCH * 2;

  k_prep<<<dim3(2048 + 3072 + 1024), 256, 0, stream>>>(x, W_qkv, W_proj, Xb, Wt_qkv, Wt_proj);
  k_qkv_gemm<<<dim3(BT / 128, N3 / 128), 256, 0, stream>>>(Xb, Wt_qkv, b_qkv, Qfb, Kfb, Vfb);
  k_attn<<<dim3(2048), 128, 0, stream>>>(Qfb, Kfb, Vfb, Yb);
  k_proj_gemm<<<dim3(BT / 128, CCH / 128), 256, 0, stream>>>(Yb, Wt_proj, b_proj, out);
}

// Round 21
// 104.759 us; speedup vs baseline: 1.1057x; 1.1057x over previous
//
#include <hip/hip_runtime.h>
#include <hip/hip_bf16.h>
#include <math.h>

#define BB 2
#define TT 2048
#define CCH 1024
#define HH 16
#define DD 64
#define BT (BB*TT)     // 4096
#define N3 (3*CCH)     // 3072

typedef __attribute__((ext_vector_type(8))) short short8;
typedef __attribute__((ext_vector_type(4))) float f32x4;
typedef __attribute__((ext_vector_type(16))) float f32x16;

__device__ __forceinline__ unsigned short f2bf(float f) {
  unsigned int u = __float_as_uint(f);
  unsigned int r = (u + 0x7FFFu + ((u >> 16) & 1u)) >> 16;  // RNE
  return (unsigned short)r;
}
__device__ __forceinline__ int cvtpk(float lo, float hi) {
  int r;
  asm("v_cvt_pk_bf16_f32 %0, %1, %2" : "=v"(r) : "v"(lo), "v"(hi));
  return r;
}
__device__ __forceinline__ void plswap(int &a, int &b) {
  asm("v_permlane32_swap_b32 %0, %1" : "+v"(a), "+v"(b));
}
__device__ __forceinline__ float fexp2(float x) {   // native v_exp_f32: 2^x, 1 inst
  float r;
  asm("v_exp_f32 %0, %1" : "=v"(r) : "v"(x));
  return r;
}
__device__ __forceinline__ void gload_lds16(const unsigned short* g, unsigned short* l) {
  __builtin_amdgcn_global_load_lds((const __attribute__((address_space(1))) void*)g,
                                   (__attribute__((address_space(3))) void*)l, 16, 0, 0);
}
__device__ __forceinline__ float fmax3(float a, float b, float c) {
  return fmaxf(fmaxf(a, b), c);   // fuses to v_max3_f32
}

// Fragment-ordered layouts (per-bh buffers of TT*DD bf16):
//  row-frag (Q and K):  addr(r, d) = ((r>>5)*4 + (d>>4))*512 + ((d>>3)&1)*256 + (r&31)*8 + (d&7)
//  col-frag (V):        addr(t, d) = (((t>>6)*2 + (d>>5))*4 + ((t>>4)&3))*512
//                                    + (((t>>3)&1)*32 + (d&31))*8 + (t&7)

// ---------------- fused prep: x->bf16 convert + both weight transposes (one launch) ----------------
__global__ __launch_bounds__(256) void k_prep(const float* __restrict__ x,
                                              const float* __restrict__ W_qkv,
                                              const float* __restrict__ W_proj,
                                              unsigned short* __restrict__ Xb,
                                              unsigned short* __restrict__ Wt_qkv,
                                              unsigned short* __restrict__ Wt_proj) {
  __shared__ float tile[32][33];
  int id = blockIdx.x;
  int tid = threadIdx.x;
  if (id < 2048) {
    int i = id * 256 + tid;
    const float4 a = *(const float4*)(x + (size_t)i * 8);
    const float4 b = *(const float4*)(x + (size_t)i * 8 + 4);
    short8 v;
    v[0] = f2bf(a.x); v[1] = f2bf(a.y); v[2] = f2bf(a.z); v[3] = f2bf(a.w);
    v[4] = f2bf(b.x); v[5] = f2bf(b.y); v[6] = f2bf(b.z); v[7] = f2bf(b.w);
    *(short8*)(Xb + (size_t)i * 8) = v;
    return;
  }
  const float* in;
  unsigned short* out;
  int R, Cn, tc, tr;
  if (id < 2048 + 3072) {             // W_qkv transpose
    int u = id - 2048;
    in = W_qkv; out = Wt_qkv; R = CCH; Cn = N3;
    tc = (u % 96) * 32; tr = (u / 96) * 32;
  } else {                            // W_proj transpose
    int u = id - 5120;
    in = W_proj; out = Wt_proj; R = CCH; Cn = CCH;
    tc = (u % 32) * 32; tr = (u / 32) * 32;
  }
  int lx = tid & 31;
  int ly = tid >> 5;
#pragma unroll
  for (int i = 0; i < 32; i += 8)
    tile[ly + i][lx] = in[(size_t)(tr + ly + i) * Cn + tc + lx];
  __syncthreads();
#pragma unroll
  for (int i = 0; i < 32; i += 8)
    out[(size_t)(tc + ly + i) * R + tr + lx] = f2bf(tile[lx][ly + i]);
}

// ---------------- QKV GEMM (m97 pattern) -> fragment-ordered Qf(scaled), Kf, Vf ----------------
__global__ __launch_bounds__(256) void k_qkv_gemm(const unsigned short* __restrict__ Xb,
                                                  const unsigned short* __restrict__ Wt,
                                                  const float* __restrict__ bias,
                                                  unsigned short* __restrict__ Qf,
                                                  unsigned short* __restrict__ Kf,
                                                  unsigned short* __restrict__ Vf) {
  __shared__ __align__(16) unsigned short As[128 * 32];
  __shared__ __align__(16) unsigned short Bs[128 * 32];
  int tid = threadIdx.x;
  int mb = blockIdx.x * 128;
  int nb = blockIdx.y * 128;
  int wid = tid >> 6, lane = tid & 63;
  int wr = (wid >> 1) * 64, wc = (wid & 1) * 64;
  int l15 = lane & 15, l4 = lane >> 4;
  int l16 = lane >> 2, lc = (lane & 3) * 8;
  f32x4 acc[4][4];
#pragma unroll
  for (int a = 0; a < 4; ++a)
#pragma unroll
    for (int b = 0; b < 4; ++b)
#pragma unroll
      for (int j = 0; j < 4; ++j) acc[a][b][j] = 0.0f;

  for (int kb = 0; kb < CCH; kb += 32) {
#pragma unroll
    for (int i = 0; i < 2; ++i) {
      int arow = wid * 32 + i * 16;
      gload_lds16(Xb + (size_t)(mb + arow + l16) * CCH + kb + lc, &As[arow * 32]);
      gload_lds16(Wt + (size_t)(nb + arow + l16) * CCH + kb + lc, &Bs[arow * 32]);
    }
    __syncthreads();
    short8 af[4], bfr[4];
#pragma unroll
    for (int mt = 0; mt < 4; ++mt) af[mt] = *(const short8*)(&As[(wr + mt * 16 + l15) * 32 + l4 * 8]);
#pragma unroll
    for (int nt = 0; nt < 4; ++nt) bfr[nt] = *(const short8*)(&Bs[(wc + nt * 16 + l15) * 32 + l4 * 8]);
#pragma unroll
    for (int mt = 0; mt < 4; ++mt)
#pragma unroll
      for (int nt = 0; nt < 4; ++nt)
        acc[mt][nt] = __builtin_amdgcn_mfma_f32_16x16x32_bf16(af[mt], bfr[nt], acc[mt][nt], 0, 0, 0);
    __syncthreads();
  }

#pragma unroll
  for (int mt = 0; mt < 4; ++mt) {
#pragma unroll
    for (int nt = 0; nt < 4; ++nt) {
      int gcol = nb + wc + nt * 16 + l15;
      int which = gcol >> 10;
      int cc = gcol & 1023;
      int hh = cc >> 6, d = cc & 63;
      float bv = bias[gcol];
#pragma unroll
      for (int j = 0; j < 4; ++j) {
        int grow = mb + wr + mt * 16 + l4 * 4 + j;
        int b = grow >> 11, t = grow & 2047;
        float v = acc[mt][nt][j] + bv;
        size_t bh = (size_t)(b * HH + hh) * TT * DD;
        if (which == 2) {
          size_t a = (size_t)((((t >> 6) * 2 + (d >> 5)) * 4 + ((t >> 4) & 3)) * 512
                             + (((t >> 3) & 1) * 32 + (d & 31)) * 8 + (t & 7));
          Vf[bh + a] = f2bf(v);
        } else {
          size_t a = (size_t)(((t >> 5) * 4 + (d >> 4)) * 512
                             + ((d >> 3) & 1) * 256 + (t & 31) * 8 + (d & 7));
          if (which == 0) Qf[bh + a] = f2bf(v * 0.18033688f);  // sm_scale * log2(e)
          else            Kf[bh + a] = f2bf(v);
        }
      }
    }
  }
}

// ---------------- causal flash attention: LDS-free, fragment-ordered operands ----------------
__global__ __launch_bounds__(128) void k_attn(const unsigned short* __restrict__ Qf,
                                              const unsigned short* __restrict__ Kf,
                                              const unsigned short* __restrict__ Vf,
                                              unsigned short* __restrict__ Y) {
  __shared__ float ex[64 * 33];     // wave-1 partial O (+1-pad rotation)
  __shared__ float exml[128];       // wave-1 m,l
  int tid = threadIdx.x;            // 0..127
  int jx = blockIdx.x;              // 0..2047
  int j = 63 - (jx >> 5);           // 32-row q-subtile, biggest jobs first
  int bh = jx & 31;
  int wid = tid >> 6, lane = tid & 63;
  int l31 = lane & 31, h = lane >> 5;
  int q0 = j * 32;
  int qrow = q0 + l31;
  int tmax = j >> 1;                // last 64-wide KV tile index

  const unsigned short* Qp = Qf + (size_t)bh * TT * DD;
  const unsigned short* Kp = Kf + (size_t)bh * TT * DD;
  const unsigned short* Vp = Vf + (size_t)bh * TT * DD;

  short8 qf[4];
#pragma unroll
  for (int m = 0; m < 4; ++m)
    qf[m] = *(const short8*)(Qp + (size_t)(j * 4 + m) * 512 + lane * 8);

  f32x16 zv;
#pragma unroll
  for (int r = 0; r < 16; ++r) zv[r] = 0.0f;
  f32x16 po[2];
  po[0] = zv; po[1] = zv;
  float mrun = -1e30f, lrun = 0.0f;

  for (int t = wid; t <= tmax; t += 2) {
    int kvb = t * 64;

    short8 kf[2][4];
#pragma unroll
    for (int t32 = 0; t32 < 2; ++t32)
#pragma unroll
      for (int m = 0; m < 4; ++m)
        kf[t32][m] = *(const short8*)(Kp + (size_t)((t * 2 + t32) * 4 + m) * 512 + lane * 8);

    f32x16 st[2];
    __builtin_amdgcn_s_setprio(1);
#pragma unroll
    for (int t32 = 0; t32 < 2; ++t32) {
      st[t32] = __builtin_amdgcn_mfma_f32_32x32x16_bf16(kf[t32][0], qf[0], zv, 0, 0, 0);
#pragma unroll
      for (int m = 1; m < 4; ++m)
        st[t32] = __builtin_amdgcn_mfma_f32_32x32x16_bf16(kf[t32][m], qf[m], st[t32], 0, 0, 0);
    }
    __builtin_amdgcn_s_setprio(0);

    short8 vf[2][4];
#pragma unroll
    for (int dt = 0; dt < 2; ++dt)
#pragma unroll
      for (int g = 0; g < 4; ++g)
        vf[dt][g] = *(const short8*)(Vp + (size_t)((t * 2 + dt) * 4 + g) * 512 + lane * 8);

    if (kvb + 63 > q0) {              // diagonal tiles: causal mask
#pragma unroll
      for (int t32 = 0; t32 < 2; ++t32)
#pragma unroll
        for (int r = 0; r < 16; ++r) {
          int kvg = kvb + t32 * 32 + (r & 3) + 8 * (r >> 2) + 4 * h;
          if (kvg > qrow) st[t32][r] = -1e30f;
        }
    }

    float A = st[0][0], B = st[0][1], C = st[0][2], Dv = st[0][3];
#pragma unroll
    for (int r = 4; r < 16; r += 4) {
      A = fmax3(A, st[0][r], st[0][r + 1]);
      B = fmax3(B, st[0][r + 2], st[0][r + 3]);
      C = fmax3(C, st[1][r - 4], st[1][r - 3]);
      Dv = fmax3(Dv, st[1][r - 2], st[1][r - 1]);
    }
    C = fmax3(C, st[1][12], st[1][13]);
    Dv = fmax3(Dv, st[1][14], st[1][15]);
    float mx = fmaxf(fmax3(A, B, C), Dv);
    mx = fmaxf(mx, __shfl_xor(mx, 32));

    if (__any(mx - mrun > 8.0f)) {    // defer-max, log2 units
      float mnew = fmaxf(mrun, mx);
      float alpha = fexp2(mrun - mnew);
      lrun *= alpha;
#pragma unroll
      for (int dt = 0; dt < 2; ++dt)
#pragma unroll
        for (int r = 0; r < 16; ++r) po[dt][r] *= alpha;
      mrun = mnew;
    }

    float sum = 0.0f;
#pragma unroll
    for (int t32 = 0; t32 < 2; ++t32)
#pragma unroll
      for (int r = 0; r < 16; ++r) {
        float p = fexp2(st[t32][r] - mrun);
        st[t32][r] = p;
        sum += p;
      }
    sum += __shfl_xor(sum, 32);
    lrun += sum;

    short8 pf[4];
#pragma unroll
    for (int g = 0; g < 4; ++g) {
      int t32 = g >> 1, r0 = (g & 1) * 8;
      int a = cvtpk(st[t32][r0 + 0], st[t32][r0 + 1]);
      int b = cvtpk(st[t32][r0 + 4], st[t32][r0 + 5]);
      plswap(a, b);
      int c = cvtpk(st[t32][r0 + 2], st[t32][r0 + 3]);
      int d = cvtpk(st[t32][r0 + 6], st[t32][r0 + 7]);
      plswap(c, d);
      union { int w[4]; short8 s; } un;
      un.w[0] = a; un.w[1] = c; un.w[2] = b; un.w[3] = d;
      pf[g] = un.s;
    }

    __builtin_amdgcn_s_setprio(1);
#pragma unroll
    for (int dt = 0; dt < 2; ++dt)
#pragma unroll
      for (int g = 0; g < 4; ++g)
        po[dt] = __builtin_amdgcn_mfma_f32_32x32x16_bf16(vf[dt][g], pf[g], po[dt], 0, 0, 0);
    __builtin_amdgcn_s_setprio(0);
  }

  __syncthreads();
  if (wid == 1) {
#pragma unroll
    for (int dt = 0; dt < 2; ++dt)
#pragma unroll
      for (int r = 0; r < 16; ++r) ex[lane * 33 + dt * 16 + r] = po[dt][r];
    exml[lane] = mrun;
    exml[64 + lane] = lrun;
  }
  __syncthreads();
  if (wid == 0) {
    float m1 = exml[lane], l1 = exml[64 + lane];
    float M = fmaxf(mrun, m1);
    float a0 = fexp2(mrun - M), a1 = fexp2(m1 - M);
    float inv = 1.0f / (lrun * a0 + l1 * a1);
    a0 *= inv; a1 *= inv;
    int b = bh >> 4, hh = bh & 15;
    unsigned short* yp = Y + ((size_t)(b * TT + qrow)) * CCH + hh * DD;
#pragma unroll
    for (int dt = 0; dt < 2; ++dt)
#pragma unroll
      for (int r = 0; r < 16; r += 2) {
        int d = dt * 32 + (r & 3) + 8 * (r >> 2) + 4 * h;
        float v0 = po[dt][r]     * a0 + ex[lane * 33 + dt * 16 + r]     * a1;
        float v1 = po[dt][r + 1] * a0 + ex[lane * 33 + dt * 16 + r + 1] * a1;
        *(int*)(yp + d) = cvtpk(v0, v1);
      }
  }
}

// ---------------- proj GEMM (m97 pattern): Yb bf16 @ Wt_proj bf16 + bias -> f32 out ----------------
__global__ __launch_bounds__(256) void k_proj_gemm(const unsigned short* __restrict__ Yb,
                                                   const unsigned short* __restrict__ Wt,
                                                   const float* __restrict__ bias,
                                                   float* __restrict__ Out) {
  __shared__ __align__(16) unsigned short As[128 * 32];
  __shared__ __align__(16) unsigned short Bs[128 * 32];
  int tid = threadIdx.x;
  int mb = blockIdx.x * 128;
  int nb = blockIdx.y * 128;
  int wid = tid >> 6, lane = tid & 63;
  int wr = (wid >> 1) * 64, wc = (wid & 1) * 64;
  int l15 = lane & 15, l4 = lane >> 4;
  int l16 = lane >> 2, lc = (lane & 3) * 8;
  f32x4 acc[4][4];
#pragma unroll
  for (int a = 0; a < 4; ++a)
#pragma unroll
    for (int b = 0; b < 4; ++b)
#pragma unroll
      for (int j = 0; j < 4; ++j) acc[a][b][j] = 0.0f;

  for (int kb = 0; kb < CCH; kb += 32) {
#pragma unroll
    for (int i = 0; i < 2; ++i) {
      int arow = wid * 32 + i * 16;
      gload_lds16(Yb + (size_t)(mb + arow + l16) * CCH + kb + lc, &As[arow * 32]);
      gload_lds16(Wt + (size_t)(nb + arow + l16) * CCH + kb + lc, &Bs[arow * 32]);
    }
    __syncthreads();
    short8 af[4], bfr[4];
#pragma unroll
    for (int mt = 0; mt < 4; ++mt) af[mt] = *(const short8*)(&As[(wr + mt * 16 + l15) * 32 + l4 * 8]);
#pragma unroll
    for (int nt = 0; nt < 4; ++nt) bfr[nt] = *(const short8*)(&Bs[(wc + nt * 16 + l15) * 32 + l4 * 8]);
#pragma unroll
    for (int mt = 0; mt < 4; ++mt)
#pragma unroll
      for (int nt = 0; nt < 4; ++nt)
        acc[mt][nt] = __builtin_amdgcn_mfma_f32_16x16x32_bf16(af[mt], bfr[nt], acc[mt][nt], 0, 0, 0);
    __syncthreads();
  }

#pragma unroll
  for (int mt = 0; mt < 4; ++mt) {
#pragma unroll
    for (int nt = 0; nt < 4; ++nt) {
      int gcol = nb + wc + nt * 16 + l15;
      float bv = bias[gcol];
#pragma unroll
      for (int j = 0; j < 4; ++j) {
        int grow = mb + wr + mt * 16 + l4 * 4 + j;
        Out[(size_t)grow * CCH + gcol] = acc[mt][nt][j] + bv;
      }
    }
  }
}

extern "C" void kernel_launch(void* const* d_in, const int* in_sizes, int n_in,
                              void* d_out, int out_size, void* d_ws, size_t ws_size,
                              hipStream_t stream) {
  const float* x      = (const float*)d_in[0];
  const float* W_qkv  = (const float*)d_in[1];
  const float* b_qkv  = (const float*)d_in[2];
  const float* W_proj = (const float*)d_in[3];
  const float* b_proj = (const float*)d_in[4];
  float* out = (float*)d_out;

  char* ws = (char*)d_ws;
  size_t off = 0;
  unsigned short* Wt_qkv  = (unsigned short*)(ws + off); off += (size_t)N3 * CCH * 2;
  unsigned short* Wt_proj = (unsigned short*)(ws + off); off += (size_t)CCH * CCH * 2;
  unsigned short* Xb      = (unsigned short*)(ws + off); off += (size_t)BT * CCH * 2;
  unsigned short* Qfb     = (unsigned short*)(ws + off); off += (size_t)BT * CCH * 2;
  unsigned short* Kfb     = (unsigned short*)(ws + off); off += (size_t)BT * CCH * 2;
  unsigned short* Vfb     = (unsigned short*)(ws + off); off += (size_t)BT * CCH * 2;
  unsigned short* Yb      = (unsigned short*)(ws + off); off += (size_t)BT * CCH * 2;

  k_prep<<<dim3(2048 + 3072 + 1024), 256, 0, stream>>>(x, W_qkv, W_proj, Xb, Wt_qkv, Wt_proj);
  k_qkv_gemm<<<dim3(BT / 128, N3 / 128), 256, 0, stream>>>(Xb, Wt_qkv, b_qkv, Qfb, Kfb, Vfb);
  k_attn<<<dim3(2048), 128, 0, stream>>>(Qfb, Kfb, Vfb, Yb);
  k_proj_gemm<<<dim3(BT / 128, CCH / 128), 256, 0, stream>>>(Yb, Wt_proj, b_proj, out);
}